// Round 2
// baseline (385.271 us; speedup 1.0000x reference)
//
#include <hip/hip_runtime.h>

// Problem constants (fixed by the reference)
#define NN 32768      // nodes
#define EE 262144     // edges
#define DM 512        // input/model dim (K of the big GEMM)
#define NQKV 1536     // q|k|v concatenated
#define NHEAD 8
#define DHEAD 64

typedef unsigned short u16;
typedef unsigned int u32;
typedef __attribute__((ext_vector_type(8))) short bf16x8;   // MFMA A/B operand (8 bf16)
typedef __attribute__((ext_vector_type(4))) float f32x4;    // MFMA C/D
typedef __attribute__((ext_vector_type(8))) u16 u16x8;
typedef __attribute__((ext_vector_type(4))) u32 u32x4;

__device__ __forceinline__ float bf2f(u16 u) {
  union { u32 i; float f; } x; x.i = ((u32)u) << 16; return x.f;
}
__device__ __forceinline__ float bflo(u32 p) {
  union { u32 i; float f; } x; x.i = p << 16; return x.f;
}
__device__ __forceinline__ float bfhi(u32 p) {
  union { u32 i; float f; } x; x.i = p & 0xFFFF0000u; return x.f;
}
__device__ __forceinline__ u16 f2bf(float f) {
  union { float f; u32 i; } x; x.f = f;
  u32 r = x.i + 0x7FFFu + ((x.i >> 16) & 1u);   // RNE
  return (u16)(r >> 16);
}

__device__ __forceinline__ void load_lds16(const u16* g, u16* l) {
  __builtin_amdgcn_global_load_lds(
      (const __attribute__((address_space(1))) char*)(const void*)g,
      (__attribute__((address_space(3))) char*)(void*)l, 16, 0, 0);
}

// XOR chunk swizzle (legacy 128^2 kernels, 32-elem rows)
__device__ __forceinline__ int swz(int r, int s) {
  return s ^ (r & 3) ^ ((r >> 2) & 1);
}

// ---------------------------------------------------------------------------
// Transpose-cast Wq/Wk/Wv -> At[perm(z,j)][m] = Wsel[m][j] * scale  (bf16)
// ---------------------------------------------------------------------------
__global__ void tcast_w(const float* __restrict__ Wq, const float* __restrict__ Wk,
                        const float* __restrict__ Wv, u16* __restrict__ At) {
  const int z = blockIdx.z;           // 0=q,1=k,2=v
  const float* W = (z == 0) ? Wq : (z == 1) ? Wk : Wv;
  const float scale = (z == 0) ? 0.125f : 1.0f;
  const int m0 = blockIdx.x * 64;     // source row block (m)
  const int j0 = blockIdx.y * 64;     // source col block (j)
  __shared__ float t[64][65];
  const int tx = threadIdx.x & 63, ty = threadIdx.x >> 6;
#pragma unroll
  for (int i = 0; i < 16; ++i) {
    const int r = ty * 16 + i;
    t[r][tx] = W[(size_t)(m0 + r) * 512 + (j0 + tx)];   // coalesced over tx
  }
  __syncthreads();
#pragma unroll
  for (int i = 0; i < 16; ++i) {
    const int j = j0 + ty * 16 + i;
    const int pr = (z == 0) ? j : (512 + 2 * j + (z - 1));  // permuted row
    At[(size_t)pr * 512 + (m0 + tx)] = f2bf(t[tx][ty * 16 + i] * scale);
  }
}

// Win fp32 -> bf16 (already [kk][m] = B^T layout for the compose GEMM)
__global__ void cast_win(const float* __restrict__ Win, u16* __restrict__ Winb) {
  const int i = (blockIdx.x * 256 + threadIdx.x) * 8;
  float4 a = *(const float4*)&Win[i];
  float4 b = *(const float4*)&Win[i + 4];
  u16x8 o = { f2bf(a.x), f2bf(a.y), f2bf(a.z), f2bf(a.w),
              f2bf(b.x), f2bf(b.y), f2bf(b.z), f2bf(b.w) };
  *(u16x8*)&Winb[i] = o;
}

__global__ void make_bias(const float* __restrict__ bin,
                          const float* __restrict__ Wq, const float* __restrict__ bq,
                          const float* __restrict__ Wk, const float* __restrict__ bk,
                          const float* __restrict__ Wv, const float* __restrict__ bv,
                          float* __restrict__ bias) {
  const int j = blockIdx.x * 256 + threadIdx.x;   // logical index
  if (j >= 1536) return;
  const float* Wsel; const float* bsel; int jj; float scale = 1.0f; int pos;
  if (j < 512)       { Wsel = Wq; bsel = bq; jj = j;        scale = 0.125f; pos = j; }
  else if (j < 1024) { Wsel = Wk; bsel = bk; jj = j - 512;  pos = 512 + 2 * jj; }
  else               { Wsel = Wv; bsel = bv; jj = j - 1024; pos = 513 + 2 * jj; }
  float s = 0.f;
  for (int m = 0; m < 512; ++m) s = fmaf(bin[m], Wsel[m * 512 + jj], s);
  bias[pos] = (s + bsel[jj]) * scale;
}

// h fp32 -> bf16 (GEMM A operand)
__global__ void cast_h(const float* __restrict__ h, u16* __restrict__ hb) {
  const int i = (blockIdx.x * 256 + threadIdx.x) * 8;
  float4 a = *(const float4*)&h[i];
  float4 b = *(const float4*)&h[i + 4];
  u16x8 o = { f2bf(a.x), f2bf(a.y), f2bf(a.z), f2bf(a.w),
              f2bf(b.x), f2bf(b.y), f2bf(b.z), f2bf(b.w) };
  *(u16x8*)&hb[i] = o;
}

// ---------------------------------------------------------------------------
// CSR build on `row`
// ---------------------------------------------------------------------------
__global__ void count_deg(const int* __restrict__ row, int* __restrict__ deg) {
  const int e = blockIdx.x * 256 + threadIdx.x;
  atomicAdd(&deg[row[e]], 1);
}

__global__ void scan_deg(const int* __restrict__ deg, int* __restrict__ row_ptr,
                         int* __restrict__ cursor) {
  __shared__ int sums[1024];
  const int t = threadIdx.x;
  const int base = t * 32;
  int loc[32];
  int s = 0;
#pragma unroll
  for (int i = 0; i < 32; ++i) { loc[i] = s; s += deg[base + i]; }
  sums[t] = s;
  __syncthreads();
  for (int off = 1; off < 1024; off <<= 1) {
    int v = (t >= off) ? sums[t - off] : 0;
    __syncthreads();
    sums[t] += v;
    __syncthreads();
  }
  const int excl = sums[t] - s;
#pragma unroll
  for (int i = 0; i < 32; ++i) {
    const int val = excl + loc[i];
    row_ptr[base + i] = val;
    cursor[base + i] = val;
  }
  if (t == 1023) row_ptr[NN] = sums[1023];
}

__global__ void fill_csr(const int* __restrict__ row, const int* __restrict__ col,
                         int* __restrict__ cursor, int* __restrict__ dst) {
  const int e = blockIdx.x * 256 + threadIdx.x;
  const int r = row[e];
  const int p = atomicAdd(&cursor[r], 1);
  dst[p] = col[e];
}

// ---------------------------------------------------------------------------
// Compose GEMM: Wt[j][kk] = sum_m At[j][m] * Winb[kk][m]
// M=1536, N=512, K=512. 128^2 + 2-phase pipeline (small; not the bottleneck).
// ---------------------------------------------------------------------------
__global__ __launch_bounds__(256, 2) void gemm_wt(
    const u16* __restrict__ A,    // At [1536][512] bf16 (rows pre-permuted)
    const u16* __restrict__ B,    // Winb [512][512] bf16 (B^T layout)
    u16* __restrict__ C) {        // Wt [1536][512] bf16
  __shared__ u16 As[2][128 * 32];
  __shared__ u16 Bs[2][128 * 32];
  const int tid = threadIdx.x;
  const int lane = tid & 63;
  const int wave = tid >> 6;
  const int quad = lane >> 4;
  const int l16 = lane & 15;
  const int m0 = blockIdx.y * 128;
  const int n0 = blockIdx.x * 128;
  const int wm = (wave >> 1) * 64;
  const int wn = (wave & 1) * 64;

  const int c0 = tid, c1 = tid + 256;
  const int r0 = c0 >> 2, ko0 = swz(r0, c0 & 3) * 8;
  const int r1 = c1 >> 2, ko1 = swz(r1, c1 & 3) * 8;
  const u16* Ag0 = A + (size_t)(m0 + r0) * DM + ko0;
  const u16* Ag1 = A + (size_t)(m0 + r1) * DM + ko1;
  const u16* Bg0 = B + (size_t)(n0 + r0) * DM + ko0;
  const u16* Bg1 = B + (size_t)(n0 + r1) * DM + ko1;

  f32x4 acc[4][4];
#pragma unroll
  for (int i = 0; i < 4; ++i)
#pragma unroll
    for (int j = 0; j < 4; ++j) acc[i][j] = (f32x4){0.f, 0.f, 0.f, 0.f};

  load_lds16(Ag0, &As[0][c0 * 8]);
  load_lds16(Bg0, &Bs[0][c0 * 8]);
  load_lds16(Ag1, &As[0][c1 * 8]);
  load_lds16(Bg1, &Bs[0][c1 * 8]);
  __syncthreads();

  int cur = 0;
#pragma unroll
  for (int kt = 32; kt < DM; kt += 32) {
    load_lds16(Ag0 + kt, &As[cur ^ 1][c0 * 8]);
    load_lds16(Bg0 + kt, &Bs[cur ^ 1][c0 * 8]);
    load_lds16(Ag1 + kt, &As[cur ^ 1][c1 * 8]);
    load_lds16(Bg1 + kt, &Bs[cur ^ 1][c1 * 8]);
    bf16x8 a[4], b[4];
#pragma unroll
    for (int i = 0; i < 4; ++i) {
      const int ra = wm + i * 16 + l16;
      const int rb = wn + i * 16 + l16;
      a[i] = *(const bf16x8*)&As[cur][ra * 32 + swz(ra, quad) * 8];
      b[i] = *(const bf16x8*)&Bs[cur][rb * 32 + swz(rb, quad) * 8];
    }
#pragma unroll
    for (int mi = 0; mi < 4; ++mi)
#pragma unroll
      for (int ni = 0; ni < 4; ++ni)
        acc[mi][ni] = __builtin_amdgcn_mfma_f32_16x16x32_bf16(a[mi], b[ni], acc[mi][ni], 0, 0, 0);
    __syncthreads();
    cur ^= 1;
  }
  {
    bf16x8 a[4], b[4];
#pragma unroll
    for (int i = 0; i < 4; ++i) {
      const int ra = wm + i * 16 + l16;
      const int rb = wn + i * 16 + l16;
      a[i] = *(const bf16x8*)&As[cur][ra * 32 + swz(ra, quad) * 8];
      b[i] = *(const bf16x8*)&Bs[cur][rb * 32 + swz(rb, quad) * 8];
    }
#pragma unroll
    for (int mi = 0; mi < 4; ++mi)
#pragma unroll
      for (int ni = 0; ni < 4; ++ni)
        acc[mi][ni] = __builtin_amdgcn_mfma_f32_16x16x32_bf16(a[mi], b[ni], acc[mi][ni], 0, 0, 0);
  }

#pragma unroll
  for (int ni = 0; ni < 4; ++ni) {
    const int coln = n0 + wn + ni * 16 + l16;
#pragma unroll
    for (int mi = 0; mi < 4; ++mi) {
#pragma unroll
      for (int r = 0; r < 4; ++r) {
        const int rowm = m0 + wm + mi * 16 + quad * 4 + r;
        C[(size_t)rowm * 512 + coln] = f2bf(acc[mi][ni][r]);
      }
    }
  }
}

// ---------------------------------------------------------------------------
// QKV = h_bf16 @ Wt^T + bias   (M=32768, N=1536, K=512)
// 256^2 tile, BK=32, 512 threads / 8 waves (2M x 4N), per-wave 128x64 output.
// 4-deep LDS ring (128 KiB): compute tile t while staging tile t+2 -> the
// tile-boundary wait is a COUNTED s_waitcnt vmcnt(4) (T3+T4), never drain-0.
// Bank swizzle: chunk ^= (r>>1)&3 on 16B chunks of 64B rows (T2), applied to
// the per-lane GLOBAL source (global_load_lds dest must stay linear, m104).
// setprio around each 16-MFMA cluster (T5). MFMA chain per output element is
// identical to the 128^2 kernel -> bit-identical numerics.
// ---------------------------------------------------------------------------
#define BKQ 32
__global__ __launch_bounds__(512, 2) void gemm_qkv(
    const u16* __restrict__ A,    // hb [32768][512] bf16, row-major
    const u16* __restrict__ B,    // Wt [1536][512] bf16, N-major, rows permuted
    const float* __restrict__ bias,  // permuted to match columns
    u16* __restrict__ C) {        // qkv [32768,1536] bf16 unified
  __shared__ u16 As[4][256 * BKQ];   // 4 x 16 KiB
  __shared__ u16 Bs[4][256 * BKQ];   // 4 x 16 KiB
  const int tid = threadIdx.x;
  const int lane = tid & 63;
  const int wave = tid >> 6;        // 0..7
  const int quad = lane >> 4;       // 0..3 (k-chunk of this lane's frag)
  const int l16 = lane & 15;
  const int wr = wave >> 2;         // 0..1 (M split)
  const int wc = wave & 3;          // 0..3 (N split)

  // XCD swizzle: 768 blocks = 8 XCDs x 96; each XCD gets 16 consecutive
  // by-panels (A reuse in its L2) x all 6 bx (B fully L2-resident).
  const int bid = blockIdx.y * 6 + blockIdx.x;
  const int sw = (bid & 7) * 96 + (bid >> 3);
  const int bx = sw % 6, by = sw / 6;
  const int m0 = by * 256, n0 = bx * 256;

  // staging: 1024 16B-slots per operand tile; thread owns slots tid, tid+512.
  // slot s -> LDS (linear, wave-uniform-base + lane*16 compatible): byte s*16
  //         -> logical (r = s>>2, chunk' = s&3); global chunk = chunk'^((r>>1)&3)
  const int sa0 = tid, sa1 = tid + 512;
  const int ra0 = sa0 >> 2, ca0 = (sa0 & 3) ^ ((ra0 >> 1) & 3);
  const int ra1 = sa1 >> 2, ca1 = (sa1 & 3) ^ ((ra1 >> 1) & 3);
  const u16* Aga = A + (size_t)(m0 + ra0) * DM + ca0 * 8;
  const u16* Agb = A + (size_t)(m0 + ra1) * DM + ca1 * 8;
  const u16* Bga = B + (size_t)(n0 + ra0) * DM + ca0 * 8;
  const u16* Bgb = B + (size_t)(n0 + ra1) * DM + ca1 * 8;

  // fragment ds_read offsets (u16 elems): row r, chunk quad^((r>>1)&3)
  int offA[8], offB[4];
#pragma unroll
  for (int mf = 0; mf < 8; ++mf) {
    const int r = wr * 128 + mf * 16 + l16;
    offA[mf] = r * BKQ + (quad ^ ((r >> 1) & 3)) * 8;
  }
#pragma unroll
  for (int nf = 0; nf < 4; ++nf) {
    const int r = wc * 64 + nf * 16 + l16;
    offB[nf] = r * BKQ + (quad ^ ((r >> 1) & 3)) * 8;
  }

  f32x4 acc[8][4];
#pragma unroll
  for (int i = 0; i < 8; ++i)
#pragma unroll
    for (int j = 0; j < 4; ++j) acc[i][j] = (f32x4){0.f, 0.f, 0.f, 0.f};

  // prologue: stage tiles 0,1 (per-thread issue order: t0.A,A,B,B, t1.A,A,B,B)
  load_lds16(Aga, &As[0][sa0 * 8]);
  load_lds16(Agb, &As[0][sa1 * 8]);
  load_lds16(Bga, &Bs[0][sa0 * 8]);
  load_lds16(Bgb, &Bs[0][sa1 * 8]);
  load_lds16(Aga + BKQ, &As[1][sa0 * 8]);
  load_lds16(Agb + BKQ, &As[1][sa1 * 8]);
  load_lds16(Bga + BKQ, &Bs[1][sa0 * 8]);
  load_lds16(Bgb + BKQ, &Bs[1][sa1 * 8]);
  // wait tile0 landed (all but newest 4 = tile1's), then release everyone
  asm volatile("s_waitcnt vmcnt(4)\n\ts_barrier" ::: "memory");

  for (int t = 0; t < 16; ++t) {
    const int bt = t & 3;
    const u16* Al = &As[bt][0];
    const u16* Bl = &Bs[bt][0];
    const int kg = (t + 2) * BKQ;
    bf16x8 a[4], b[4];

    // ---- phase 0: A-frags mf0-3 + all B-frags; stage A(t+2) ----
#pragma unroll
    for (int i = 0; i < 4; ++i) a[i] = *(const bf16x8*)&Al[offA[i]];
#pragma unroll
    for (int i = 0; i < 4; ++i) b[i] = *(const bf16x8*)&Bl[offB[i]];
    if (t < 14) {
      const int b2 = (t + 2) & 3;
      load_lds16(Aga + kg, &As[b2][sa0 * 8]);
      load_lds16(Agb + kg, &As[b2][sa1 * 8]);
    }
    __builtin_amdgcn_s_barrier();
    __builtin_amdgcn_s_setprio(1);
#pragma unroll
    for (int mi = 0; mi < 4; ++mi)
#pragma unroll
      for (int ni = 0; ni < 4; ++ni)
        acc[mi][ni] = __builtin_amdgcn_mfma_f32_16x16x32_bf16(a[mi], b[ni], acc[mi][ni], 0, 0, 0);
    __builtin_amdgcn_s_setprio(0);
    __builtin_amdgcn_s_barrier();

    // ---- phase 1: A-frags mf4-7 (reuse b); stage B(t+2) ----
#pragma unroll
    for (int i = 0; i < 4; ++i) a[i] = *(const bf16x8*)&Al[offA[4 + i]];
    if (t < 14) {
      const int b2 = (t + 2) & 3;
      load_lds16(Bga + kg, &Bs[b2][sa0 * 8]);
      load_lds16(Bgb + kg, &Bs[b2][sa1 * 8]);
    }
    __builtin_amdgcn_s_barrier();
    __builtin_amdgcn_s_setprio(1);
#pragma unroll
    for (int mi = 0; mi < 4; ++mi)
#pragma unroll
      for (int ni = 0; ni < 4; ++ni)
        acc[4 + mi][ni] = __builtin_amdgcn_mfma_f32_16x16x32_bf16(a[mi], b[ni], acc[4 + mi][ni], 0, 0, 0);
    __builtin_amdgcn_s_setprio(0);

    // ---- tile boundary: counted wait (tile t+1 landed; t+2 stays in flight)
    if (t < 14) {
      asm volatile("s_waitcnt vmcnt(4)\n\ts_barrier" ::: "memory");
    } else if (t == 14) {
      asm volatile("s_waitcnt vmcnt(0)\n\ts_barrier" ::: "memory");
    }
  }

  // epilogue: C/D layout col=lane&15 (n side), row=quad*4+r (m side)
#pragma unroll
  for (int nf = 0; nf < 4; ++nf) {
    const int coln = n0 + wc * 64 + nf * 16 + l16;
    const float bv = bias[coln];
#pragma unroll
    for (int mf = 0; mf < 8; ++mf) {
#pragma unroll
      for (int r = 0; r < 4; ++r) {
        const int rowm = m0 + wr * 128 + mf * 16 + quad * 4 + r;
        C[(size_t)rowm * NQKV + coln] = f2bf(acc[mf][nf][r] + bv);
      }
    }
  }
}

// ---------------------------------------------------------------------------
// Fused sparse attention: ONE WAVE PER NODE; lane l owns dims l*8..l*8+7.
// CSR walk fully scalarized (readfirstlane node -> s_loads for row_ptr/dst),
// next-chunk indices prefetched under current chunk's gather+compute, and
// tail edges (deg % 4) processed singly -> no padded 2KB gathers (~19% of
// gather traffic was padding at mean degree 8).
// ---------------------------------------------------------------------------
__global__ __launch_bounds__(256) void attn_agg(
    const u16* __restrict__ qkv16, const u32* __restrict__ qkv32,
    const int* __restrict__ row_ptr, const int* __restrict__ dst,
    float* __restrict__ out) {
  const int gt = blockIdx.x * 256 + threadIdx.x;
  const int lane = gt & 63;
  const int node = __builtin_amdgcn_readfirstlane(gt >> 6);  // wave-uniform

  const u16x8 qr = *(const u16x8*)&qkv16[(size_t)node * NQKV + lane * 8];
  float qf[8];
#pragma unroll
  for (int j = 0; j < 8; ++j) qf[j] = bf2f(qr[j]);

  const int beg = row_ptr[node];
  const int end = row_ptr[node + 1];
  float acc[8] = {0.f,0.f,0.f,0.f,0.f,0.f,0.f,0.f};
  float denom = 0.f;

  int e = beg;
  if (e + 4 <= end) {
    int idx[4];
#pragma unroll
    for (int jj = 0; jj < 4; ++jj) idx[jj] = dst[e + jj];
    for (; e + 4 <= end; e += 4) {
      // prefetch next chunk's indices (clamped inside this row; discarded at exit)
      const int lim = end - 1;
      int idxn[4];
#pragma unroll
      for (int jj = 0; jj < 4; ++jj) idxn[jj] = dst[min(e + 4 + jj, lim)];
      u32 p[4][8];
#pragma unroll
      for (int jj = 0; jj < 4; ++jj) {
        const u32* pp = qkv32 + (size_t)idx[jj] * 768 + 256 + lane * 8;
        *(u32x4*)&p[jj][0] = *(const u32x4*)pp;        // dwordx4
        *(u32x4*)&p[jj][4] = *(const u32x4*)(pp + 4);  // dwordx4
      }
#pragma unroll
      for (int jj = 0; jj < 4; ++jj) {
        float s = 0.f;
#pragma unroll
        for (int j = 0; j < 8; ++j) s = fmaf(qf[j], bflo(p[jj][j]), s);
        s += __shfl_xor(s, 1, 64);   // reduce within the 8-lane head group
        s += __shfl_xor(s, 2, 64);
        s += __shfl_xor(s, 4, 64);
        const float ex = __expf(s);
        denom += ex;
#pragma unroll
        for (int j = 0; j < 8; ++j) acc[j] = fmaf(ex, bfhi(p[jj][j]), acc[j]);
      }
#pragma unroll
      for (int jj = 0; jj < 4; ++jj) idx[jj] = idxn[jj];
    }
  }
  // tail: 0..3 remaining edges, processed singly (no padded gathers)
  for (; e < end; ++e) {
    const int id = dst[e];
    const u32* pp = qkv32 + (size_t)id * 768 + 256 + lane * 8;
    u32 p[8];
    *(u32x4*)&p[0] = *(const u32x4*)pp;
    *(u32x4*)&p[4] = *(const u32x4*)(pp + 4);
    float s = 0.f;
#pragma unroll
    for (int j = 0; j < 8; ++j) s = fmaf(qf[j], bflo(p[j]), s);
    s += __shfl_xor(s, 1, 64);
    s += __shfl_xor(s, 2, 64);
    s += __shfl_xor(s, 4, 64);
    const float ex = __expf(s);
    denom += ex;
#pragma unroll
    for (int j = 0; j < 8; ++j) acc[j] = fmaf(ex, bfhi(p[j]), acc[j]);
  }

  const float inv = (end > beg) ? (1.0f / denom) : 0.f;   // deg-0 rows -> 0
  float4 o0 = { acc[0] * inv, acc[1] * inv, acc[2] * inv, acc[3] * inv };
  float4 o1 = { acc[4] * inv, acc[5] * inv, acc[6] * inv, acc[7] * inv };
  float* op = &out[(size_t)node * 512 + lane * 8];
  *(float4*)op = o0;
  *(float4*)(op + 4) = o1;
}

// ---------------------------------------------------------------------------
extern "C" void kernel_launch(void* const* d_in, const int* in_sizes, int n_in,
                              void* d_out, int out_size, void* d_ws, size_t ws_size,
                              hipStream_t stream) {
  const float* h   = (const float*)d_in[0];
  const int*   row = (const int*)d_in[1];
  const int*   col = (const int*)d_in[2];
  const float* Win = (const float*)d_in[3];
  const float* bin = (const float*)d_in[4];
  const float* Wq  = (const float*)d_in[5];
  const float* bq  = (const float*)d_in[6];
  const float* Wk  = (const float*)d_in[7];
  const float* bk  = (const float*)d_in[8];
  const float* Wv  = (const float*)d_in[9];
  const float* bv  = (const float*)d_in[10];
  float* out = (float*)d_out;

  char* ws = (char*)d_ws;
  u16*   qkv     = (u16*)(ws + 0);           // 32768*1536*2 = 100,663,296
  u16*   hb      = (u16*)(ws + 100663296);   // 32768*512*2  =  33,554,432
  u16*   Wt      = (u16*)(ws + 134217728);   // 1536*512*2   =   1,572,864
  float* bias    = (float*)(ws + 135790592); // 1536*4
  int*   deg     = (int*)(ws + 135796736);   // 32768*4
  int*   row_ptr = (int*)(ws + 135927808);   // 32769*4 (+pad)
  int*   cursor  = (int*)(ws + 136058888);   // 32768*4
  int*   dst     = (int*)(ws + 136189960);   // 262144*4
  // transient (aliased into qkv region; consumed by gemm_wt BEFORE gemm_qkv
  // writes qkv — same-stream ordering makes this safe):
  u16*   At      = (u16*)(ws + 0);           // 1536*512*2 = 1,572,864
  u16*   Winb    = (u16*)(ws + 1572864);     //  512*512*2 =   524,288

  (void)hipMemsetAsync(deg, 0, NN * sizeof(int), stream);
  hipLaunchKernelGGL(tcast_w,   dim3(8, 8, 3), dim3(256), 0, stream, Wq, Wk, Wv, At);
  hipLaunchKernelGGL(cast_win,  dim3((512 * 512 / 8) / 256), dim3(256), 0, stream, Win, Winb);
  hipLaunchKernelGGL(make_bias, dim3(6), dim3(256), 0, stream, bin, Wq, bq, Wk, bk, Wv, bv, bias);
  hipLaunchKernelGGL(cast_h,    dim3((NN * DM / 8) / 256), dim3(256), 0, stream, h, hb);
  hipLaunchKernelGGL(count_deg, dim3(EE / 256), dim3(256), 0, stream, row, deg);
  hipLaunchKernelGGL(scan_deg,  dim3(1), dim3(1024), 0, stream, deg, row_ptr, cursor);
  hipLaunchKernelGGL(fill_csr,  dim3(EE / 256), dim3(256), 0, stream, row, col, cursor, dst);
  hipLaunchKernelGGL(gemm_wt,   dim3(512 / 128, 1536 / 128), dim3(256), 0, stream, At, Winb, Wt);
  hipLaunchKernelGGL(gemm_qkv,  dim3(NQKV / 256, NN / 256), dim3(512), 0, stream, hb, Wt, bias, qkv);
  hipLaunchKernelGGL(attn_agg,  dim3((NN * 64) / 256), dim3(256), 0, stream,
                     qkv, (const u32*)qkv, row_ptr, dst, out);
}

// Round 3
// 339.664 us; speedup vs baseline: 1.1343x; 1.1343x over previous
//
#include <hip/hip_runtime.h>

// Problem constants (fixed by the reference)
#define NN 32768      // nodes
#define EE 262144     // edges
#define DM 512        // input/model dim (K of the big GEMM)
#define NQKV 1536     // q|k|v concatenated
#define NHEAD 8
#define DHEAD 64

typedef unsigned short u16;
typedef unsigned int u32;
typedef __attribute__((ext_vector_type(8))) short bf16x8;   // MFMA A/B operand (8 bf16)
typedef __attribute__((ext_vector_type(4))) float f32x4;    // MFMA C/D
typedef __attribute__((ext_vector_type(8))) u16 u16x8;
typedef __attribute__((ext_vector_type(4))) u32 u32x4;

__device__ __forceinline__ float bf2f(u16 u) {
  union { u32 i; float f; } x; x.i = ((u32)u) << 16; return x.f;
}
__device__ __forceinline__ float bflo(u32 p) {
  union { u32 i; float f; } x; x.i = p << 16; return x.f;
}
__device__ __forceinline__ float bfhi(u32 p) {
  union { u32 i; float f; } x; x.i = p & 0xFFFF0000u; return x.f;
}
__device__ __forceinline__ u16 f2bf(float f) {
  union { float f; u32 i; } x; x.f = f;
  u32 r = x.i + 0x7FFFu + ((x.i >> 16) & 1u);   // RNE
  return (u16)(r >> 16);
}

__device__ __forceinline__ void load_lds16(const u16* g, u16* l) {
  __builtin_amdgcn_global_load_lds(
      (const __attribute__((address_space(1))) char*)(const void*)g,
      (__attribute__((address_space(3))) char*)(void*)l, 16, 0, 0);
}

// XOR chunk swizzle for the 4x16B chunks of a 32-elem LDS row.
__device__ __forceinline__ int swz(int r, int s) {
  return s ^ (r & 3) ^ ((r >> 2) & 1);
}

// ---------------------------------------------------------------------------
// prep_all: all independent preprocessing in ONE launch (block-range dispatch)
//   [0, 8192)            cast_h    : h fp32 -> bf16
//   [8192, 8320)         cast_win  : Win fp32 -> bf16 (B^T layout)
//   [8320, 9344)         count_deg : degree histogram of `row`
//   [9344, 9536)         tcast_w   : transpose-cast Wq/Wk/Wv -> At (permuted)
//   [9536, 9632)         make_bias : bias partials (16-way K-split, atomicAdd)
// Output column permutation: q_j -> j; k_d -> 512+2d; v_d -> 513+2d.
// ---------------------------------------------------------------------------
#define GB_CASTH 8192
#define GB_CASTW 128
#define GB_CNTD  1024
#define GB_TCW   192
#define GB_BIAS  96
__global__ void prep_all(const float* __restrict__ h, u16* __restrict__ hb,
                         const float* __restrict__ Win, u16* __restrict__ Winb,
                         const int* __restrict__ row, int* __restrict__ deg,
                         const float* __restrict__ Wq, const float* __restrict__ Wk,
                         const float* __restrict__ Wv, u16* __restrict__ At,
                         const float* __restrict__ bin, const float* __restrict__ bq,
                         const float* __restrict__ bk, const float* __restrict__ bv,
                         float* __restrict__ bias) {
  __shared__ float t[64][65];
  const int tid = threadIdx.x;
  int b = blockIdx.x;

  if (b < GB_CASTH) {                       // ---- cast_h ----
    const int i = (b * 256 + tid) * 8;
    float4 a = *(const float4*)&h[i];
    float4 c = *(const float4*)&h[i + 4];
    u16x8 o = { f2bf(a.x), f2bf(a.y), f2bf(a.z), f2bf(a.w),
                f2bf(c.x), f2bf(c.y), f2bf(c.z), f2bf(c.w) };
    *(u16x8*)&hb[i] = o;
    return;
  }
  b -= GB_CASTH;
  if (b < GB_CASTW) {                       // ---- cast_win ----
    const int i = (b * 256 + tid) * 8;
    float4 a = *(const float4*)&Win[i];
    float4 c = *(const float4*)&Win[i + 4];
    u16x8 o = { f2bf(a.x), f2bf(a.y), f2bf(a.z), f2bf(a.w),
                f2bf(c.x), f2bf(c.y), f2bf(c.z), f2bf(c.w) };
    *(u16x8*)&Winb[i] = o;
    return;
  }
  b -= GB_CASTW;
  if (b < GB_CNTD) {                        // ---- count_deg ----
    const int e = b * 256 + tid;
    atomicAdd(&deg[row[e]], 1);
    return;
  }
  b -= GB_CNTD;
  if (b < GB_TCW) {                         // ---- tcast_w ----
    const int z = b / 64;                   // 0=q,1=k,2=v
    const int r64 = b % 64;
    const float* W = (z == 0) ? Wq : (z == 1) ? Wk : Wv;
    const float scale = (z == 0) ? 0.125f : 1.0f;
    const int m0 = (r64 >> 3) * 64;
    const int j0 = (r64 & 7) * 64;
    const int tx = tid & 63, ty = tid >> 6;
#pragma unroll
    for (int i = 0; i < 16; ++i) {
      const int r = ty * 16 + i;
      t[r][tx] = W[(size_t)(m0 + r) * 512 + (j0 + tx)];   // coalesced over tx
    }
    __syncthreads();
#pragma unroll
    for (int i = 0; i < 16; ++i) {
      const int j = j0 + ty * 16 + i;
      const int pr = (z == 0) ? j : (512 + 2 * j + (z - 1));  // permuted row
      At[(size_t)pr * 512 + (m0 + tx)] = f2bf(t[tx][ty * 16 + i] * scale);
    }
    return;
  }
  b -= GB_TCW;
  {                                         // ---- make_bias partial ----
    const int j = (b % 6) * 256 + tid;      // logical output index 0..1535
    const int m0 = (b / 6) * 32;            // this block's K-slice
    const float* Wsel; const float* bsel; int jj; float scale = 1.0f; int pos;
    if (j < 512)       { Wsel = Wq; bsel = bq; jj = j;        scale = 0.125f; pos = j; }
    else if (j < 1024) { Wsel = Wk; bsel = bk; jj = j - 512;  pos = 512 + 2 * jj; }
    else               { Wsel = Wv; bsel = bv; jj = j - 1024; pos = 513 + 2 * jj; }
    float s0 = 0.f, s1 = 0.f, s2 = 0.f, s3 = 0.f;
#pragma unroll
    for (int m = 0; m < 32; m += 4) {
      s0 = fmaf(bin[m0 + m],     Wsel[(size_t)(m0 + m)     * 512 + jj], s0);
      s1 = fmaf(bin[m0 + m + 1], Wsel[(size_t)(m0 + m + 1) * 512 + jj], s1);
      s2 = fmaf(bin[m0 + m + 2], Wsel[(size_t)(m0 + m + 2) * 512 + jj], s2);
      s3 = fmaf(bin[m0 + m + 3], Wsel[(size_t)(m0 + m + 3) * 512 + jj], s3);
    }
    float add = ((s0 + s1) + (s2 + s3)) * scale;
    if (m0 == 0) add += bsel[jj] * scale;
    atomicAdd(&bias[pos], add);
  }
}

// ---------------------------------------------------------------------------
// CSR build on `row` (scan + fill; counting folded into prep_all)
// ---------------------------------------------------------------------------
__global__ void scan_deg(const int* __restrict__ deg, int* __restrict__ row_ptr,
                         int* __restrict__ cursor) {
  __shared__ int sums[1024];
  const int t = threadIdx.x;
  const int base = t * 32;
  int loc[32];
  int s = 0;
#pragma unroll
  for (int i = 0; i < 32; ++i) { loc[i] = s; s += deg[base + i]; }
  sums[t] = s;
  __syncthreads();
  for (int off = 1; off < 1024; off <<= 1) {
    int v = (t >= off) ? sums[t - off] : 0;
    __syncthreads();
    sums[t] += v;
    __syncthreads();
  }
  const int excl = sums[t] - s;
#pragma unroll
  for (int i = 0; i < 32; ++i) {
    const int val = excl + loc[i];
    row_ptr[base + i] = val;
    cursor[base + i] = val;
  }
  if (t == 1023) row_ptr[NN] = sums[1023];
}

__global__ void fill_csr(const int* __restrict__ row, const int* __restrict__ col,
                         int* __restrict__ cursor, int* __restrict__ dst) {
  const int e = blockIdx.x * 256 + threadIdx.x;
  const int r = row[e];
  const int p = atomicAdd(&cursor[r], 1);
  dst[p] = col[e];
}

// ---------------------------------------------------------------------------
// Compose GEMM: Wt[j][kk] = sum_m At[j][m] * Winb[kk][m]
// M=1536, N=512, K=512. 128^2 + 2-phase pipeline.
// ---------------------------------------------------------------------------
__global__ __launch_bounds__(256, 2) void gemm_wt(
    const u16* __restrict__ A,    // At [1536][512] bf16 (rows pre-permuted)
    const u16* __restrict__ B,    // Winb [512][512] bf16 (B^T layout)
    u16* __restrict__ C) {        // Wt [1536][512] bf16
  __shared__ u16 As[2][128 * 32];
  __shared__ u16 Bs[2][128 * 32];
  const int tid = threadIdx.x;
  const int lane = tid & 63;
  const int wave = tid >> 6;
  const int quad = lane >> 4;
  const int l16 = lane & 15;
  const int m0 = blockIdx.y * 128;
  const int n0 = blockIdx.x * 128;
  const int wm = (wave >> 1) * 64;
  const int wn = (wave & 1) * 64;

  const int c0 = tid, c1 = tid + 256;
  const int r0 = c0 >> 2, ko0 = swz(r0, c0 & 3) * 8;
  const int r1 = c1 >> 2, ko1 = swz(r1, c1 & 3) * 8;
  const u16* Ag0 = A + (size_t)(m0 + r0) * DM + ko0;
  const u16* Ag1 = A + (size_t)(m0 + r1) * DM + ko1;
  const u16* Bg0 = B + (size_t)(n0 + r0) * DM + ko0;
  const u16* Bg1 = B + (size_t)(n0 + r1) * DM + ko1;

  f32x4 acc[4][4];
#pragma unroll
  for (int i = 0; i < 4; ++i)
#pragma unroll
    for (int j = 0; j < 4; ++j) acc[i][j] = (f32x4){0.f, 0.f, 0.f, 0.f};

  load_lds16(Ag0, &As[0][c0 * 8]);
  load_lds16(Bg0, &Bs[0][c0 * 8]);
  load_lds16(Ag1, &As[0][c1 * 8]);
  load_lds16(Bg1, &Bs[0][c1 * 8]);
  __syncthreads();

  int cur = 0;
#pragma unroll
  for (int kt = 32; kt < DM; kt += 32) {
    load_lds16(Ag0 + kt, &As[cur ^ 1][c0 * 8]);
    load_lds16(Bg0 + kt, &Bs[cur ^ 1][c0 * 8]);
    load_lds16(Ag1 + kt, &As[cur ^ 1][c1 * 8]);
    load_lds16(Bg1 + kt, &Bs[cur ^ 1][c1 * 8]);
    bf16x8 a[4], b[4];
#pragma unroll
    for (int i = 0; i < 4; ++i) {
      const int ra = wm + i * 16 + l16;
      const int rb = wn + i * 16 + l16;
      a[i] = *(const bf16x8*)&As[cur][ra * 32 + swz(ra, quad) * 8];
      b[i] = *(const bf16x8*)&Bs[cur][rb * 32 + swz(rb, quad) * 8];
    }
#pragma unroll
    for (int mi = 0; mi < 4; ++mi)
#pragma unroll
      for (int ni = 0; ni < 4; ++ni)
        acc[mi][ni] = __builtin_amdgcn_mfma_f32_16x16x32_bf16(a[mi], b[ni], acc[mi][ni], 0, 0, 0);
    __syncthreads();
    cur ^= 1;
  }
  {
    bf16x8 a[4], b[4];
#pragma unroll
    for (int i = 0; i < 4; ++i) {
      const int ra = wm + i * 16 + l16;
      const int rb = wn + i * 16 + l16;
      a[i] = *(const bf16x8*)&As[cur][ra * 32 + swz(ra, quad) * 8];
      b[i] = *(const bf16x8*)&Bs[cur][rb * 32 + swz(rb, quad) * 8];
    }
#pragma unroll
    for (int mi = 0; mi < 4; ++mi)
#pragma unroll
      for (int ni = 0; ni < 4; ++ni)
        acc[mi][ni] = __builtin_amdgcn_mfma_f32_16x16x32_bf16(a[mi], b[ni], acc[mi][ni], 0, 0, 0);
  }

#pragma unroll
  for (int ni = 0; ni < 4; ++ni) {
    const int coln = n0 + wn + ni * 16 + l16;
#pragma unroll
    for (int mi = 0; mi < 4; ++mi) {
#pragma unroll
      for (int r = 0; r < 4; ++r) {
        const int rowm = m0 + wm + mi * 16 + quad * 4 + r;
        C[(size_t)rowm * 512 + coln] = f2bf(acc[mi][ni][r]);
      }
    }
  }
}

// ---------------------------------------------------------------------------
// QKV = h_bf16 @ Wt^T + bias   (M=32768, N=1536, K=512)
// Round-1 proven structure: 128^2 tile, 2-phase double-buffer (stage t+1
// before compute t), XCD-aware bijective swizzle (3072 % 8 == 0).
// ---------------------------------------------------------------------------
__global__ __launch_bounds__(256, 2) void gemm_qkv(
    const u16* __restrict__ A,    // [32768,512] bf16, row-major
    const u16* __restrict__ B,    // [1536,512] bf16, N-major, rows permuted
    const float* __restrict__ bias,  // permuted to match columns
    u16* __restrict__ C) {        // qkv [32768,1536] bf16 unified
  __shared__ u16 As[2][128 * 32];
  __shared__ u16 Bs[2][128 * 32];
  const int tid = threadIdx.x;
  const int lane = tid & 63;
  const int wave = tid >> 6;
  const int quad = lane >> 4;
  const int l16 = lane & 15;

  const int bid = blockIdx.y * 12 + blockIdx.x;
  const int sw = (bid & 7) * 384 + (bid >> 3);
  const int bx = sw % 12;
  const int by = sw / 12;
  const int m0 = by * 128;
  const int n0 = bx * 128;
  const int wm = (wave >> 1) * 64;
  const int wn = (wave & 1) * 64;

  const int c0 = tid, c1 = tid + 256;
  const int r0 = c0 >> 2, ko0 = swz(r0, c0 & 3) * 8;
  const int r1 = c1 >> 2, ko1 = swz(r1, c1 & 3) * 8;
  const u16* Ag0 = A + (size_t)(m0 + r0) * DM + ko0;
  const u16* Ag1 = A + (size_t)(m0 + r1) * DM + ko1;
  const u16* Bg0 = B + (size_t)(n0 + r0) * DM + ko0;
  const u16* Bg1 = B + (size_t)(n0 + r1) * DM + ko1;

  f32x4 acc[4][4];
#pragma unroll
  for (int i = 0; i < 4; ++i)
#pragma unroll
    for (int j = 0; j < 4; ++j) acc[i][j] = (f32x4){0.f, 0.f, 0.f, 0.f};

  load_lds16(Ag0, &As[0][c0 * 8]);
  load_lds16(Bg0, &Bs[0][c0 * 8]);
  load_lds16(Ag1, &As[0][c1 * 8]);
  load_lds16(Bg1, &Bs[0][c1 * 8]);
  __syncthreads();

  int cur = 0;
#pragma unroll
  for (int kt = 32; kt < DM; kt += 32) {
    load_lds16(Ag0 + kt, &As[cur ^ 1][c0 * 8]);
    load_lds16(Bg0 + kt, &Bs[cur ^ 1][c0 * 8]);
    load_lds16(Ag1 + kt, &As[cur ^ 1][c1 * 8]);
    load_lds16(Bg1 + kt, &Bs[cur ^ 1][c1 * 8]);
    bf16x8 a[4], b[4];
#pragma unroll
    for (int i = 0; i < 4; ++i) {
      const int ra = wm + i * 16 + l16;
      const int rb = wn + i * 16 + l16;
      a[i] = *(const bf16x8*)&As[cur][ra * 32 + swz(ra, quad) * 8];
      b[i] = *(const bf16x8*)&Bs[cur][rb * 32 + swz(rb, quad) * 8];
    }
#pragma unroll
    for (int mi = 0; mi < 4; ++mi)
#pragma unroll
      for (int ni = 0; ni < 4; ++ni)
        acc[mi][ni] = __builtin_amdgcn_mfma_f32_16x16x32_bf16(a[mi], b[ni], acc[mi][ni], 0, 0, 0);
    __syncthreads();
    cur ^= 1;
  }
  {
    bf16x8 a[4], b[4];
#pragma unroll
    for (int i = 0; i < 4; ++i) {
      const int ra = wm + i * 16 + l16;
      const int rb = wn + i * 16 + l16;
      a[i] = *(const bf16x8*)&As[cur][ra * 32 + swz(ra, quad) * 8];
      b[i] = *(const bf16x8*)&Bs[cur][rb * 32 + swz(rb, quad) * 8];
    }
#pragma unroll
    for (int mi = 0; mi < 4; ++mi)
#pragma unroll
      for (int ni = 0; ni < 4; ++ni)
        acc[mi][ni] = __builtin_amdgcn_mfma_f32_16x16x32_bf16(a[mi], b[ni], acc[mi][ni], 0, 0, 0);
  }

  // epilogue: C/D layout col=lane&15, row=quad*4+r (verified m89/m91)
#pragma unroll
  for (int ni = 0; ni < 4; ++ni) {
    const int coln = n0 + wn + ni * 16 + l16;
    const float bv = bias[coln];
#pragma unroll
    for (int mi = 0; mi < 4; ++mi) {
#pragma unroll
      for (int r = 0; r < 4; ++r) {
        const int rowm = m0 + wm + mi * 16 + quad * 4 + r;
        C[(size_t)rowm * NQKV + coln] = f2bf(acc[mi][ni][r] + bv);
      }
    }
  }
}

// ---------------------------------------------------------------------------
// Fused sparse attention: ONE WAVE PER NODE; lane l owns dims l*8..l*8+7.
// CHUNK=8: one gather-latency exposure covers a typical row (mean degree 8) —
// 16 independent dwordx4 in flight before the first dependent use. Tail edges
// clamp to the last real edge (duplicate gathers are L1/L2 hits; padded terms
// masked with ex=0, so numerics are bit-identical).
// ---------------------------------------------------------------------------
__global__ __launch_bounds__(256) void attn_agg(
    const u16* __restrict__ qkv16, const u32* __restrict__ qkv32,
    const int* __restrict__ row_ptr, const int* __restrict__ dst,
    float* __restrict__ out) {
  const int gt = blockIdx.x * 256 + threadIdx.x;
  const int node = gt >> 6;
  const int lane = gt & 63;
  const int beg = row_ptr[node];
  const int end = row_ptr[node + 1];

  const u16x8 qr = *(const u16x8*)&qkv16[(size_t)node * NQKV + lane * 8];
  float qf[8];
#pragma unroll
  for (int j = 0; j < 8; ++j) qf[j] = bf2f(qr[j]);

  float acc[8] = {0.f,0.f,0.f,0.f,0.f,0.f,0.f,0.f};
  float denom = 0.f;

  for (int e = beg; e < end; e += 8) {
    const int lim = end - 1;
    int idx[8];
#pragma unroll
    for (int jj = 0; jj < 8; ++jj) idx[jj] = dst[min(e + jj, lim)];
    u32 p[8][8];
#pragma unroll
    for (int jj = 0; jj < 8; ++jj) {
      const u32* pp = qkv32 + (size_t)idx[jj] * 768 + 256 + lane * 8;
      *(u32x4*)&p[jj][0] = *(const u32x4*)pp;        // dwordx4
      *(u32x4*)&p[jj][4] = *(const u32x4*)(pp + 4);  // dwordx4
    }
#pragma unroll
    for (int jj = 0; jj < 8; ++jj) {
      float s = 0.f;
#pragma unroll
      for (int j = 0; j < 8; ++j) s = fmaf(qf[j], bflo(p[jj][j]), s);
      s += __shfl_xor(s, 1, 64);   // reduce within the 8-lane head group
      s += __shfl_xor(s, 2, 64);
      s += __shfl_xor(s, 4, 64);
      const float ex = (e + jj <= lim) ? __expf(s) : 0.f;
      denom += ex;
#pragma unroll
      for (int j = 0; j < 8; ++j) acc[j] = fmaf(ex, bfhi(p[jj][j]), acc[j]);
    }
  }

  const float inv = (end > beg) ? (1.0f / denom) : 0.f;   // deg-0 rows -> 0
  float4 o0 = { acc[0] * inv, acc[1] * inv, acc[2] * inv, acc[3] * inv };
  float4 o1 = { acc[4] * inv, acc[5] * inv, acc[6] * inv, acc[7] * inv };
  float* op = &out[(size_t)node * 512 + lane * 8];
  *(float4*)op = o0;
  *(float4*)(op + 4) = o1;
}

// ---------------------------------------------------------------------------
extern "C" void kernel_launch(void* const* d_in, const int* in_sizes, int n_in,
                              void* d_out, int out_size, void* d_ws, size_t ws_size,
                              hipStream_t stream) {
  const float* h   = (const float*)d_in[0];
  const int*   row = (const int*)d_in[1];
  const int*   col = (const int*)d_in[2];
  const float* Win = (const float*)d_in[3];
  const float* bin = (const float*)d_in[4];
  const float* Wq  = (const float*)d_in[5];
  const float* bq  = (const float*)d_in[6];
  const float* Wk  = (const float*)d_in[7];
  const float* bk  = (const float*)d_in[8];
  const float* Wv  = (const float*)d_in[9];
  const float* bv  = (const float*)d_in[10];
  float* out = (float*)d_out;

  char* ws = (char*)d_ws;
  u16*   qkv     = (u16*)(ws + 0);           // 32768*1536*2 = 100,663,296
  u16*   hb      = (u16*)(ws + 100663296);   // 32768*512*2  =  33,554,432
  u16*   Wt      = (u16*)(ws + 134217728);   // 1536*512*2   =   1,572,864
  float* bias    = (float*)(ws + 135790592); // 1536*4
  int*   deg     = (int*)(ws + 135796736);   // 32768*4
  int*   row_ptr = (int*)(ws + 135927808);   // 32769*4 (+pad)
  int*   cursor  = (int*)(ws + 136058888);   // 32768*4
  int*   dst     = (int*)(ws + 136189960);   // 262144*4
  // transient (aliased into qkv region; consumed by gemm_wt BEFORE gemm_qkv
  // writes qkv — same-stream ordering makes this safe):
  u16*   At      = (u16*)(ws + 0);           // 1536*512*2 = 1,572,864
  u16*   Winb    = (u16*)(ws + 1572864);     //  512*512*2 =   524,288

  (void)hipMemsetAsync(deg, 0, NN * sizeof(int), stream);
  (void)hipMemsetAsync(bias, 0, NQKV * sizeof(float), stream);
  hipLaunchKernelGGL(prep_all,
                     dim3(GB_CASTH + GB_CASTW + GB_CNTD + GB_TCW + GB_BIAS),
                     dim3(256), 0, stream,
                     h, hb, Win, Winb, row, deg, Wq, Wk, Wv, At,
                     bin, bq, bk, bv, bias);
  hipLaunchKernelGGL(scan_deg,  dim3(1), dim3(1024), 0, stream, deg, row_ptr, cursor);
  hipLaunchKernelGGL(fill_csr,  dim3(EE / 256), dim3(256), 0, stream, row, col, cursor, dst);
  hipLaunchKernelGGL(gemm_wt,   dim3(512 / 128, 1536 / 128), dim3(256), 0, stream, At, Winb, Wt);
  hipLaunchKernelGGL(gemm_qkv,  dim3(NQKV / 128, NN / 128), dim3(256), 0, stream, hb, Wt, bias, qkv);
  hipLaunchKernelGGL(attn_agg,  dim3((NN * 64) / 256), dim3(256), 0, stream,
                     qkv, (const u32*)qkv, row_ptr, dst, out);
}

// Round 5
// 338.836 us; speedup vs baseline: 1.1370x; 1.0024x over previous
//
#include <hip/hip_runtime.h>

// Problem constants (fixed by the reference)
#define NN 32768      // nodes
#define EE 262144     // edges
#define DM 512        // input/model dim (K of the big GEMM)
#define NQKV 1536     // q|k|v concatenated
#define NHEAD 8
#define DHEAD 64

typedef unsigned short u16;
typedef unsigned int u32;
typedef __attribute__((ext_vector_type(8))) short bf16x8;   // MFMA A/B operand (8 bf16)
typedef __attribute__((ext_vector_type(4))) float f32x4;    // MFMA C/D
typedef __attribute__((ext_vector_type(8))) u16 u16x8;
typedef __attribute__((ext_vector_type(4))) u32 u32x4;

__device__ __forceinline__ float bf2f(u16 u) {
  union { u32 i; float f; } x; x.i = ((u32)u) << 16; return x.f;
}
__device__ __forceinline__ float bflo(u32 p) {
  union { u32 i; float f; } x; x.i = p << 16; return x.f;
}
__device__ __forceinline__ float bfhi(u32 p) {
  union { u32 i; float f; } x; x.i = p & 0xFFFF0000u; return x.f;
}
__device__ __forceinline__ u16 f2bf(float f) {
  union { float f; u32 i; } x; x.f = f;
  u32 r = x.i + 0x7FFFu + ((x.i >> 16) & 1u);   // RNE
  return (u16)(r >> 16);
}

__device__ __forceinline__ void load_lds16(const u16* g, u16* l) {
  __builtin_amdgcn_global_load_lds(
      (const __attribute__((address_space(1))) char*)(const void*)g,
      (__attribute__((address_space(3))) char*)(void*)l, 16, 0, 0);
}

// XOR chunk swizzle for the 4x16B chunks of a 32-elem LDS row.
__device__ __forceinline__ int swz(int r, int s) {
  return s ^ (r & 3) ^ ((r >> 2) & 1);
}

// ---------------------------------------------------------------------------
// prep_all: all independent preprocessing in ONE launch (block-range dispatch)
// ---------------------------------------------------------------------------
#define GB_CASTH 8192
#define GB_CASTW 128
#define GB_CNTD  1024
#define GB_TCW   192
#define GB_BIAS  96
__global__ void prep_all(const float* __restrict__ h, u16* __restrict__ hb,
                         const float* __restrict__ Win, u16* __restrict__ Winb,
                         const int* __restrict__ row, int* __restrict__ deg,
                         const float* __restrict__ Wq, const float* __restrict__ Wk,
                         const float* __restrict__ Wv, u16* __restrict__ At,
                         const float* __restrict__ bin, const float* __restrict__ bq,
                         const float* __restrict__ bk, const float* __restrict__ bv,
                         float* __restrict__ bias) {
  __shared__ float t[64][65];
  const int tid = threadIdx.x;
  int b = blockIdx.x;

  if (b < GB_CASTH) {                       // ---- cast_h ----
    const int i = (b * 256 + tid) * 8;
    float4 a = *(const float4*)&h[i];
    float4 c = *(const float4*)&h[i + 4];
    u16x8 o = { f2bf(a.x), f2bf(a.y), f2bf(a.z), f2bf(a.w),
                f2bf(c.x), f2bf(c.y), f2bf(c.z), f2bf(c.w) };
    *(u16x8*)&hb[i] = o;
    return;
  }
  b -= GB_CASTH;
  if (b < GB_CASTW) {                       // ---- cast_win ----
    const int i = (b * 256 + tid) * 8;
    float4 a = *(const float4*)&Win[i];
    float4 c = *(const float4*)&Win[i + 4];
    u16x8 o = { f2bf(a.x), f2bf(a.y), f2bf(a.z), f2bf(a.w),
                f2bf(c.x), f2bf(c.y), f2bf(c.z), f2bf(c.w) };
    *(u16x8*)&Winb[i] = o;
    return;
  }
  b -= GB_CASTW;
  if (b < GB_CNTD) {                        // ---- count_deg ----
    const int e = b * 256 + tid;
    atomicAdd(&deg[row[e]], 1);
    return;
  }
  b -= GB_CNTD;
  if (b < GB_TCW) {                         // ---- tcast_w ----
    const int z = b / 64;                   // 0=q,1=k,2=v
    const int r64 = b % 64;
    const float* W = (z == 0) ? Wq : (z == 1) ? Wk : Wv;
    const float scale = (z == 0) ? 0.125f : 1.0f;
    const int m0 = (r64 >> 3) * 64;
    const int j0 = (r64 & 7) * 64;
    const int tx = tid & 63, ty = tid >> 6;
#pragma unroll
    for (int i = 0; i < 16; ++i) {
      const int r = ty * 16 + i;
      t[r][tx] = W[(size_t)(m0 + r) * 512 + (j0 + tx)];   // coalesced over tx
    }
    __syncthreads();
#pragma unroll
    for (int i = 0; i < 16; ++i) {
      const int j = j0 + ty * 16 + i;
      const int pr = (z == 0) ? j : (512 + 2 * j + (z - 1));  // permuted row
      At[(size_t)pr * 512 + (m0 + tx)] = f2bf(t[tx][ty * 16 + i] * scale);
    }
    return;
  }
  b -= GB_TCW;
  {                                         // ---- make_bias partial ----
    const int j = (b % 6) * 256 + tid;      // logical output index 0..1535
    const int m0 = (b / 6) * 32;            // this block's K-slice
    const float* Wsel; const float* bsel; int jj; float scale = 1.0f; int pos;
    if (j < 512)       { Wsel = Wq; bsel = bq; jj = j;        scale = 0.125f; pos = j; }
    else if (j < 1024) { Wsel = Wk; bsel = bk; jj = j - 512;  pos = 512 + 2 * jj; }
    else               { Wsel = Wv; bsel = bv; jj = j - 1024; pos = 513 + 2 * jj; }
    float s0 = 0.f, s1 = 0.f, s2 = 0.f, s3 = 0.f;
#pragma unroll
    for (int m = 0; m < 32; m += 4) {
      s0 = fmaf(bin[m0 + m],     Wsel[(size_t)(m0 + m)     * 512 + jj], s0);
      s1 = fmaf(bin[m0 + m + 1], Wsel[(size_t)(m0 + m + 1) * 512 + jj], s1);
      s2 = fmaf(bin[m0 + m + 2], Wsel[(size_t)(m0 + m + 2) * 512 + jj], s2);
      s3 = fmaf(bin[m0 + m + 3], Wsel[(size_t)(m0 + m + 3) * 512 + jj], s3);
    }
    float add = ((s0 + s1) + (s2 + s3)) * scale;
    if (m0 == 0) add += bsel[jj] * scale;
    atomicAdd(&bias[pos], add);
  }
}

// ---------------------------------------------------------------------------
// CSR build on `row` (scan + fill; counting folded into prep_all)
// ---------------------------------------------------------------------------
__global__ void scan_deg(const int* __restrict__ deg, int* __restrict__ row_ptr,
                         int* __restrict__ cursor) {
  __shared__ int sums[1024];
  const int t = threadIdx.x;
  const int base = t * 32;
  int loc[32];
  int s = 0;
#pragma unroll
  for (int i = 0; i < 32; ++i) { loc[i] = s; s += deg[base + i]; }
  sums[t] = s;
  __syncthreads();
  for (int off = 1; off < 1024; off <<= 1) {
    int v = (t >= off) ? sums[t - off] : 0;
    __syncthreads();
    sums[t] += v;
    __syncthreads();
  }
  const int excl = sums[t] - s;
#pragma unroll
  for (int i = 0; i < 32; ++i) {
    const int val = excl + loc[i];
    row_ptr[base + i] = val;
    cursor[base + i] = val;
  }
  if (t == 1023) row_ptr[NN] = sums[1023];
}

__global__ void fill_csr(const int* __restrict__ row, const int* __restrict__ col,
                         int* __restrict__ cursor, int* __restrict__ dst) {
  const int e = blockIdx.x * 256 + threadIdx.x;
  const int r = row[e];
  const int p = atomicAdd(&cursor[r], 1);
  dst[p] = col[e];
}

// ---------------------------------------------------------------------------
// Compose GEMM: Wt[j][kk] = sum_m At[j][m] * Winb[kk][m]
// M=1536, N=512, K=512. 128^2 + 2-phase pipeline (round-3 proven form).
// ---------------------------------------------------------------------------
__global__ __launch_bounds__(256, 2) void gemm_wt(
    const u16* __restrict__ A,    // At [1536][512] bf16 (rows pre-permuted)
    const u16* __restrict__ B,    // Winb [512][512] bf16 (B^T layout)
    u16* __restrict__ C) {        // Wt [1536][512] bf16
  __shared__ u16 As[2][128 * 32];
  __shared__ u16 Bs[2][128 * 32];
  const int tid = threadIdx.x;
  const int lane = tid & 63;
  const int wave = tid >> 6;
  const int quad = lane >> 4;
  const int l16 = lane & 15;
  const int m0 = blockIdx.y * 128;
  const int n0 = blockIdx.x * 128;
  const int wm = (wave >> 1) * 64;
  const int wn = (wave & 1) * 64;

  const int c0 = tid, c1 = tid + 256;
  const int r0 = c0 >> 2, ko0 = swz(r0, c0 & 3) * 8;
  const int r1 = c1 >> 2, ko1 = swz(r1, c1 & 3) * 8;
  const u16* Ag0 = A + (size_t)(m0 + r0) * DM + ko0;
  const u16* Ag1 = A + (size_t)(m0 + r1) * DM + ko1;
  const u16* Bg0 = B + (size_t)(n0 + r0) * DM + ko0;
  const u16* Bg1 = B + (size_t)(n0 + r1) * DM + ko1;

  f32x4 acc[4][4];
#pragma unroll
  for (int i = 0; i < 4; ++i)
#pragma unroll
    for (int j = 0; j < 4; ++j) acc[i][j] = (f32x4){0.f, 0.f, 0.f, 0.f};

  load_lds16(Ag0, &As[0][c0 * 8]);
  load_lds16(Bg0, &Bs[0][c0 * 8]);
  load_lds16(Ag1, &As[0][c1 * 8]);
  load_lds16(Bg1, &Bs[0][c1 * 8]);
  __syncthreads();

  int cur = 0;
#pragma unroll
  for (int kt = 32; kt < DM; kt += 32) {
    load_lds16(Ag0 + kt, &As[cur ^ 1][c0 * 8]);
    load_lds16(Bg0 + kt, &Bs[cur ^ 1][c0 * 8]);
    load_lds16(Ag1 + kt, &As[cur ^ 1][c1 * 8]);
    load_lds16(Bg1 + kt, &Bs[cur ^ 1][c1 * 8]);
    bf16x8 a[4], b[4];
#pragma unroll
    for (int i = 0; i < 4; ++i) {
      const int ra = wm + i * 16 + l16;
      const int rb = wn + i * 16 + l16;
      a[i] = *(const bf16x8*)&As[cur][ra * 32 + swz(ra, quad) * 8];
      b[i] = *(const bf16x8*)&Bs[cur][rb * 32 + swz(rb, quad) * 8];
    }
#pragma unroll
    for (int mi = 0; mi < 4; ++mi)
#pragma unroll
      for (int ni = 0; ni < 4; ++ni)
        acc[mi][ni] = __builtin_amdgcn_mfma_f32_16x16x32_bf16(a[mi], b[ni], acc[mi][ni], 0, 0, 0);
    __syncthreads();
    cur ^= 1;
  }
  {
    bf16x8 a[4], b[4];
#pragma unroll
    for (int i = 0; i < 4; ++i) {
      const int ra = wm + i * 16 + l16;
      const int rb = wn + i * 16 + l16;
      a[i] = *(const bf16x8*)&As[cur][ra * 32 + swz(ra, quad) * 8];
      b[i] = *(const bf16x8*)&Bs[cur][rb * 32 + swz(rb, quad) * 8];
    }
#pragma unroll
    for (int mi = 0; mi < 4; ++mi)
#pragma unroll
      for (int ni = 0; ni < 4; ++ni)
        acc[mi][ni] = __builtin_amdgcn_mfma_f32_16x16x32_bf16(a[mi], b[ni], acc[mi][ni], 0, 0, 0);
  }

#pragma unroll
  for (int ni = 0; ni < 4; ++ni) {
    const int coln = n0 + wn + ni * 16 + l16;
#pragma unroll
    for (int mi = 0; mi < 4; ++mi) {
#pragma unroll
      for (int r = 0; r < 4; ++r) {
        const int rowm = m0 + wm + mi * 16 + quad * 4 + r;
        C[(size_t)rowm * 512 + coln] = f2bf(acc[mi][ni][r]);
      }
    }
  }
}

// ---------------------------------------------------------------------------
// QKV = h_bf16 @ Wt^T + bias   (M=32768, N=1536, K=512)
// 128^2 tile + XCD-aware bijective swizzle + ring-3 LDS (48 KiB, 3 blocks/CU)
// with COUNTED vmcnt. ROUND-4 FIX: the barrier asm now also drains lgkmcnt(0).
// Without it, a wave could reach the barrier with its ds_reads of tile t-1
// still in flight (compiler may sink MFMAs + their lgkm waits past inline-asm
// barriers, rule #18), and stage(t+2) -> buf[(t-1)%3] would overwrite LDS
// words mid-read (round-4 absmax fail). lgkmcnt(0) guarantees this wave's
// fragment data is in registers before anyone can overwrite that buffer;
// ds_reads were issued ~16 MFMAs earlier so the drain is ~free. vmcnt stays
// counted (4 = next tile's loads remain in flight across the barrier).
// ---------------------------------------------------------------------------
__global__ __launch_bounds__(256, 2) void gemm_qkv(
    const u16* __restrict__ A,    // [32768,512] bf16, row-major
    const u16* __restrict__ B,    // [1536,512] bf16, N-major, rows permuted
    const float* __restrict__ bias,  // permuted to match columns
    u16* __restrict__ C) {        // qkv [32768,1536] bf16 unified
  __shared__ u16 As[3][128 * 32];
  __shared__ u16 Bs[3][128 * 32];
  const int tid = threadIdx.x;
  const int lane = tid & 63;
  const int wave = tid >> 6;
  const int quad = lane >> 4;
  const int l16 = lane & 15;

  const int bid = blockIdx.y * 12 + blockIdx.x;
  const int sw = (bid & 7) * 384 + (bid >> 3);
  const int bx = sw % 12;
  const int by = sw / 12;
  const int m0 = by * 128;
  const int n0 = bx * 128;
  const int wm = (wave >> 1) * 64;
  const int wn = (wave & 1) * 64;

  const int c0 = tid, c1 = tid + 256;
  const int r0 = c0 >> 2, ko0 = swz(r0, c0 & 3) * 8;
  const int r1 = c1 >> 2, ko1 = swz(r1, c1 & 3) * 8;
  const u16* Ag0 = A + (size_t)(m0 + r0) * DM + ko0;
  const u16* Ag1 = A + (size_t)(m0 + r1) * DM + ko1;
  const u16* Bg0 = B + (size_t)(n0 + r0) * DM + ko0;
  const u16* Bg1 = B + (size_t)(n0 + r1) * DM + ko1;

  f32x4 acc[4][4];
#pragma unroll
  for (int i = 0; i < 4; ++i)
#pragma unroll
    for (int j = 0; j < 4; ++j) acc[i][j] = (f32x4){0.f, 0.f, 0.f, 0.f};

  // prologue: stage tiles 0,1 (4 loads per tile per thread)
  load_lds16(Ag0, &As[0][c0 * 8]);
  load_lds16(Bg0, &Bs[0][c0 * 8]);
  load_lds16(Ag1, &As[0][c1 * 8]);
  load_lds16(Bg1, &Bs[0][c1 * 8]);
  load_lds16(Ag0 + 32, &As[1][c0 * 8]);
  load_lds16(Bg0 + 32, &Bs[1][c0 * 8]);
  load_lds16(Ag1 + 32, &As[1][c1 * 8]);
  load_lds16(Bg1 + 32, &Bs[1][c1 * 8]);

#pragma unroll
  for (int t = 0; t < 16; ++t) {
    const int bt = t % 3;
    // counted wait: tile t landed (oldest 4), tile t+1 stays in flight;
    // lgkmcnt(0) = this wave's prior ds_reads done -> overwrite-safe.
    if (t < 15) asm volatile("s_waitcnt vmcnt(4) lgkmcnt(0)\n\ts_barrier" ::: "memory");
    else        asm volatile("s_waitcnt vmcnt(0) lgkmcnt(0)\n\ts_barrier" ::: "memory");
    // stage t+2 into buf[(t+2)%3] = buf[(t-1)%3]; all reads of tile t-1
    // completed before the barrier above (lgkmcnt(0) drained them).
    if (t < 14) {
      const int b2 = (t + 2) % 3;
      const int kg = (t + 2) * 32;
      load_lds16(Ag0 + kg, &As[b2][c0 * 8]);
      load_lds16(Bg0 + kg, &Bs[b2][c0 * 8]);
      load_lds16(Ag1 + kg, &As[b2][c1 * 8]);
      load_lds16(Bg1 + kg, &Bs[b2][c1 * 8]);
    }
    bf16x8 a[4], b[4];
#pragma unroll
    for (int i = 0; i < 4; ++i) {
      const int ra = wm + i * 16 + l16;
      const int rb = wn + i * 16 + l16;
      a[i] = *(const bf16x8*)&As[bt][ra * 32 + swz(ra, quad) * 8];
      b[i] = *(const bf16x8*)&Bs[bt][rb * 32 + swz(rb, quad) * 8];
    }
#pragma unroll
    for (int mi = 0; mi < 4; ++mi)
#pragma unroll
      for (int ni = 0; ni < 4; ++ni)
        acc[mi][ni] = __builtin_amdgcn_mfma_f32_16x16x32_bf16(a[mi], b[ni], acc[mi][ni], 0, 0, 0);
  }

  // epilogue: C/D layout col=lane&15, row=quad*4+r (verified m89/m91)
#pragma unroll
  for (int ni = 0; ni < 4; ++ni) {
    const int coln = n0 + wn + ni * 16 + l16;
    const float bv = bias[coln];
#pragma unroll
    for (int mi = 0; mi < 4; ++mi) {
#pragma unroll
      for (int r = 0; r < 4; ++r) {
        const int rowm = m0 + wm + mi * 16 + quad * 4 + r;
        C[(size_t)rowm * NQKV + coln] = f2bf(acc[mi][ni][r] + bv);
      }
    }
  }
}

// ---------------------------------------------------------------------------
// Fused sparse attention: ONE WAVE PER NODE; lane l owns dims l*8..l*8+7.
// Round-1 proven form (CHUNK=4 clamped, VGPR 48): fastest of the three
// measured structural variants (88-91 us, FETCH pinned 267 MB -> gather-bound).
// ---------------------------------------------------------------------------
__global__ __launch_bounds__(256) void attn_agg(
    const u16* __restrict__ qkv16, const u32* __restrict__ qkv32,
    const int* __restrict__ row_ptr, const int* __restrict__ dst,
    float* __restrict__ out) {
  const int gt = blockIdx.x * 256 + threadIdx.x;
  const int node = gt >> 6;
  const int lane = gt & 63;
  const u16x8 qr = *(const u16x8*)&qkv16[(size_t)node * NQKV + lane * 8];
  float qf[8];
#pragma unroll
  for (int j = 0; j < 8; ++j) qf[j] = bf2f(qr[j]);

  const int beg = row_ptr[node];
  const int end = row_ptr[node + 1];
  float acc[8] = {0.f,0.f,0.f,0.f,0.f,0.f,0.f,0.f};
  float denom = 0.f;

  for (int e = beg; e < end; e += 4) {
    u32 p[4][8];
    int idx[4];
#pragma unroll
    for (int jj = 0; jj < 4; ++jj) {
      const int ee = min(e + jj, end - 1);
      idx[jj] = dst[ee];
    }
#pragma unroll
    for (int jj = 0; jj < 4; ++jj) {
      const u32* pp = qkv32 + (size_t)idx[jj] * 768 + 256 + lane * 8;
      *(u32x4*)&p[jj][0] = *(const u32x4*)pp;        // dwordx4
      *(u32x4*)&p[jj][4] = *(const u32x4*)(pp + 4);  // dwordx4
    }
#pragma unroll
    for (int jj = 0; jj < 4; ++jj) {
      float s = 0.f;
#pragma unroll
      for (int j = 0; j < 8; ++j) s = fmaf(qf[j], bflo(p[jj][j]), s);
      s += __shfl_xor(s, 1, 64);   // reduce within the 8-lane head group
      s += __shfl_xor(s, 2, 64);
      s += __shfl_xor(s, 4, 64);
      const float ex = (e + jj < end) ? __expf(s) : 0.f;
      denom += ex;
#pragma unroll
      for (int j = 0; j < 8; ++j) acc[j] = fmaf(ex, bfhi(p[jj][j]), acc[j]);
    }
  }

  const float inv = (end > beg) ? (1.0f / denom) : 0.f;   // deg-0 rows -> 0
  float4 o0 = { acc[0] * inv, acc[1] * inv, acc[2] * inv, acc[3] * inv };
  float4 o1 = { acc[4] * inv, acc[5] * inv, acc[6] * inv, acc[7] * inv };
  float* op = &out[(size_t)node * 512 + lane * 8];
  *(float4*)op = o0;
  *(float4*)(op + 4) = o1;
}

// ---------------------------------------------------------------------------
extern "C" void kernel_launch(void* const* d_in, const int* in_sizes, int n_in,
                              void* d_out, int out_size, void* d_ws, size_t ws_size,
                              hipStream_t stream) {
  const float* h   = (const float*)d_in[0];
  const int*   row = (const int*)d_in[1];
  const int*   col = (const int*)d_in[2];
  const float* Win = (const float*)d_in[3];
  const float* bin = (const float*)d_in[4];
  const float* Wq  = (const float*)d_in[5];
  const float* bq  = (const float*)d_in[6];
  const float* Wk  = (const float*)d_in[7];
  const float* bk  = (const float*)d_in[8];
  const float* Wv  = (const float*)d_in[9];
  const float* bv  = (const float*)d_in[10];
  float* out = (float*)d_out;

  char* ws = (char*)d_ws;
  u16*   qkv     = (u16*)(ws + 0);           // 32768*1536*2 = 100,663,296
  u16*   hb      = (u16*)(ws + 100663296);   // 32768*512*2  =  33,554,432
  u16*   Wt      = (u16*)(ws + 134217728);   // 1536*512*2   =   1,572,864
  float* bias    = (float*)(ws + 135790592); // 1536*4
  int*   deg     = (int*)(ws + 135796736);   // 32768*4
  int*   row_ptr = (int*)(ws + 135927808);   // 32769*4 (+pad)
  int*   cursor  = (int*)(ws + 136058888);   // 32768*4
  int*   dst     = (int*)(ws + 136189960);   // 262144*4
  // transient (aliased into qkv region; consumed by gemm_wt BEFORE gemm_qkv
  // writes qkv — same-stream ordering makes this safe):
  u16*   At      = (u16*)(ws + 0);           // 1536*512*2 = 1,572,864
  u16*   Winb    = (u16*)(ws + 1572864);     //  512*512*2 =   524,288

  (void)hipMemsetAsync(deg, 0, NN * sizeof(int), stream);
  (void)hipMemsetAsync(bias, 0, NQKV * sizeof(float), stream);
  hipLaunchKernelGGL(prep_all,
                     dim3(GB_CASTH + GB_CASTW + GB_CNTD + GB_TCW + GB_BIAS),
                     dim3(256), 0, stream,
                     h, hb, Win, Winb, row, deg, Wq, Wk, Wv, At,
                     bin, bq, bk, bv, bias);
  hipLaunchKernelGGL(scan_deg,  dim3(1), dim3(1024), 0, stream, deg, row_ptr, cursor);
  hipLaunchKernelGGL(fill_csr,  dim3(EE / 256), dim3(256), 0, stream, row, col, cursor, dst);
  hipLaunchKernelGGL(gemm_wt,   dim3(512 / 128, 1536 / 128), dim3(256), 0, stream, At, Winb, Wt);
  hipLaunchKernelGGL(gemm_qkv,  dim3(NQKV / 128, NN / 128), dim3(256), 0, stream, hb, Wt, bias, qkv);
  hipLaunchKernelGGL(attn_agg,  dim3((NN * 64) / 256), dim3(256), 0, stream,
                     qkv, (const u32*)qkv, row_ptr, dst, out);
}